// Round 2
// baseline (987.850 us; speedup 1.0000x reference)
//
#include <hip/hip_runtime.h>

// Problem constants
constexpr int Bn = 16, Cd = 256, Hn = 64, Wn = 64, Kc = 1024;
constexpr int QUANT_ELEMS = Bn * Hn * Wn * Cd;   // 16777216
constexpr int LOSS_OFF = QUANT_ELEMS;            // +0 codebook_loss, +1 commitment_loss
constexpr int IDX_OFF = QUANT_ELEMS + 2;         // 65536 indices (stored as float)

typedef _Float16 half8 __attribute__((ext_vector_type(8)));
typedef float f32x4 __attribute__((ext_vector_type(4)));

// ws layout (bytes):
//   cbFh   @ 0        : 512 KB  (fp16 hi codebook, MFMA B-fragment-linear)
//   cbFl   @ 512K     : 512 KB  (fp16 lo residual)
//   c2     @ 1M       : 4 KB
//   cnt    @ 1M+4K    : 4 B  (flagged-row count)
//   rows   @ 1M+8K    : 256 KB (flagged row ids)
//   idxint @ 1M+8K+256K : 256 KB (final int indices)
constexpr size_t WS_CBFH = 0;
constexpr size_t WS_CBFL = 512 * 1024;
constexpr size_t WS_C2   = 1024 * 1024;
constexpr size_t WS_CNT  = 1024 * 1024 + 4096;
constexpr size_t WS_ROWS = 1024 * 1024 + 8192;
constexpr size_t WS_IDX  = 1024 * 1024 + 8192 + 262144;

// Sortable-uint key helpers: monotone in float value, idx in low 10 bits.
__device__ __forceinline__ unsigned key_of(float d, int code) {
    unsigned u = __float_as_uint(d);
    u ^= (unsigned)((int)u >> 31) | 0x80000000u;
    return (u & 0xFFFFFC00u) | (unsigned)code;
}
__device__ __forceinline__ float key_val(unsigned k) {
    unsigned u = k & 0xFFFFFC00u;
    u ^= (u & 0x80000000u) ? 0x80000000u : 0xFFFFFFFFu;
    return __uint_as_float(u);
}

// ---------------------------------------------------------------------------
// Prep: split codebook into fp16 hi/lo in MFMA B-fragment-linear layout.
// B frag (16x16x32 f16): lane l holds B[k = (l>>4)*8 + j][n = l&15], j=0..7.
// Entry e = ((ntile*8 + kblk)*64 + lane); code = ntile*16+(l&15), c = kblk*32+(l>>4)*8+j.
__global__ __launch_bounds__(256) void cb_frag(const float* __restrict__ cb,
                                               _Float16* __restrict__ cbFh,
                                               _Float16* __restrict__ cbFl,
                                               int* __restrict__ cnt) {
    const int e = blockIdx.x * 256 + threadIdx.x;   // 32768 entries
    const int ntile = e >> 9;
    const int kblk = (e >> 6) & 7;
    const int l = e & 63;
    const int code = ntile * 16 + (l & 15);
    const int cbase = kblk * 32 + (l >> 4) * 8;
    half8 hh, ll;
    #pragma unroll
    for (int j = 0; j < 8; ++j) {
        const float v = cb[(size_t)code * Cd + cbase + j];
        const _Float16 h = (_Float16)v;
        hh[j] = h;
        ll[j] = (_Float16)(v - (float)h);
    }
    *(half8*)(cbFh + (size_t)e * 8) = hh;
    *(half8*)(cbFl + (size_t)e * 8) = ll;
    if (e == 0) cnt[0] = 0;
}

// c2[k] = ||codebook_k||^2 + zero the loss outputs.
__global__ __launch_bounds__(256) void c2_kernel(const float* __restrict__ cb,
                                                 float* __restrict__ c2,
                                                 float* __restrict__ out) {
    const int tid = threadIdx.x;
    const int k = blockIdx.x * 4 + (tid >> 6);
    const int lane = tid & 63;
    float s = 0.f;
    #pragma unroll
    for (int j = 0; j < 4; ++j) {
        const float v = cb[(size_t)k * Cd + lane + 64 * j];
        s += v * v;
    }
    #pragma unroll
    for (int off = 32; off >= 1; off >>= 1) s += __shfl_xor(s, off);
    if (lane == 0) c2[k] = s;
    if (blockIdx.x == 0 && tid == 0) { out[LOSS_OFF] = 0.f; out[LOSS_OFF + 1] = 0.f; }
}

// ---------------------------------------------------------------------------
// Main: block = one (b,h) = 64 rows. 4 waves = 2 row-groups x 2 code-groups.
// Wave tile: 32 rows (2 m-tiles) x 128 codes (8 n-tiles), mfma_f32_16x16x32_f16,
// 3-term fp16 split (hh, hl, lh), fp32 accumulate. 4 code sweeps of 256.
// A: fp32 staged+transposed in LDS (fragment-linear, 2 16B planes per 8-float
// lane entry), split to fp16 at fragment load. B: fp16 pair streamed from ws.
__global__ __launch_bounds__(256, 2) void vq_main(const float* __restrict__ x,
                                                  const _Float16* __restrict__ cbFh,
                                                  const _Float16* __restrict__ cbFl,
                                                  const float* __restrict__ c2,
                                                  float* __restrict__ out,
                                                  int* __restrict__ idx_int,
                                                  int* __restrict__ cnt,
                                                  int* __restrict__ rows) {
    __shared__ float4 Aimg[1024];      // 16 KB: [sub(2)][gmt(4)][plane(2)][lane(64)]
    __shared__ unsigned q1s[2][64], q2s[2][64];

    const int tid = threadIdx.x;
    const int lane = tid & 63;
    const int wv = tid >> 6;
    const int rowgrp = wv >> 1;        // 0,1 -> rows rowgrp*32..+31
    const int codegrp = wv & 1;        // 0,1 -> codes halves of 256-sweep
    const int bh = blockIdx.x;
    const int b = bh >> 6, h = bh & 63;

    // staging coords
    const int s_rowq = tid & 15;       // w0 = 4*s_rowq
    const int s_cq = tid >> 4;         // c' = 4*s_cq (0..60)

    unsigned q1[8], q2[8];
    #pragma unroll
    for (int i = 0; i < 8; ++i) { q1[i] = 0xFFFFFFFFu; q2[i] = 0xFFFFFFFFu; }

    for (int sweep = 0; sweep < 4; ++sweep) {
        f32x4 acc[2][8];
        #pragma unroll
        for (int mt = 0; mt < 2; ++mt)
            #pragma unroll
            for (int nt = 0; nt < 8; ++nt) acc[mt][nt] = (f32x4){0.f, 0.f, 0.f, 0.f};

        for (int chunk = 0; chunk < 4; ++chunk) {
            const int c0 = chunk * 64;
            __syncthreads();
            {   // stage A: 64 rows x 64 c fp32, transposed to fragment-linear
                const int w0 = s_rowq * 4;
                const int cc = s_cq * 4;
                float4 f4[4];
                #pragma unroll
                for (int i = 0; i < 4; ++i)
                    f4[i] = *(const float4*)&x[(((size_t)b * Cd + c0 + cc + i) * Hn + h) * Wn + w0];
                const int sub = cc >> 5;
                const int cr = cc & 31;
                const int g = cr >> 3;
                const int plane = (cr >> 2) & 1;
                #pragma unroll
                for (int r = 0; r < 4; ++r) {
                    const int m = w0 + r;
                    const int gmt = m >> 4, m15 = m & 15;
                    float4 ent;
                    ent.x = f4[0].x; ent.y = f4[1].x; ent.z = f4[2].x; ent.w = f4[3].x;
                    // gather component r of each load:
                    const float* fp = (const float*)f4;
                    ent.x = fp[0 * 4 + r]; ent.y = fp[1 * 4 + r];
                    ent.z = fp[2 * 4 + r]; ent.w = fp[3 * 4 + r];
                    Aimg[((sub * 4 + gmt) * 2 + plane) * 64 + ((g << 4) | m15)] = ent;
                }
            }
            __syncthreads();

            for (int ks = 0; ks < 2; ++ks) {
                const int kblk = chunk * 2 + ks;
                half8 bhf[8], blf[8];
                #pragma unroll
                for (int nt = 0; nt < 8; ++nt) {
                    const int ntile = sweep * 16 + codegrp * 8 + nt;
                    const size_t be = ((size_t)(ntile * 8 + kblk) * 64 + lane) * 8;
                    bhf[nt] = *(const half8*)(cbFh + be);
                    blf[nt] = *(const half8*)(cbFl + be);
                }
                half8 ahf[2], alf[2];
                #pragma unroll
                for (int mt = 0; mt < 2; ++mt) {
                    const int base = ((ks * 4 + rowgrp * 2 + mt) * 2) * 64 + lane;
                    const float4 p0 = Aimg[base];
                    const float4 p1 = Aimg[base + 64];
                    const float av[8] = {p0.x, p0.y, p0.z, p0.w, p1.x, p1.y, p1.z, p1.w};
                    #pragma unroll
                    for (int j = 0; j < 8; ++j) {
                        const _Float16 hh = (_Float16)av[j];
                        ahf[mt][j] = hh;
                        alf[mt][j] = (_Float16)(av[j] - (float)hh);
                    }
                }
                // 3 terms, dependent MFMAs spaced 16 apart
                #pragma unroll
                for (int nt = 0; nt < 8; ++nt)
                    #pragma unroll
                    for (int mt = 0; mt < 2; ++mt)
                        acc[mt][nt] = __builtin_amdgcn_mfma_f32_16x16x32_f16(ahf[mt], bhf[nt], acc[mt][nt], 0, 0, 0);
                #pragma unroll
                for (int nt = 0; nt < 8; ++nt)
                    #pragma unroll
                    for (int mt = 0; mt < 2; ++mt)
                        acc[mt][nt] = __builtin_amdgcn_mfma_f32_16x16x32_f16(ahf[mt], blf[nt], acc[mt][nt], 0, 0, 0);
                #pragma unroll
                for (int nt = 0; nt < 8; ++nt)
                    #pragma unroll
                    for (int mt = 0; mt < 2; ++mt)
                        acc[mt][nt] = __builtin_amdgcn_mfma_f32_16x16x32_f16(alf[mt], bhf[nt], acc[mt][nt], 0, 0, 0);
            }
        }

        // fold sweep's 256 codes into per-row top-2 keys
        #pragma unroll
        for (int nt = 0; nt < 8; ++nt) {
            const int ntile = sweep * 16 + codegrp * 8 + nt;
            const int code = ntile * 16 + (lane & 15);
            const float c2v = c2[code];
            #pragma unroll
            for (int mt = 0; mt < 2; ++mt) {
                #pragma unroll
                for (int reg = 0; reg < 4; ++reg) {
                    const float d = fmaf(-2.f, acc[mt][nt][reg], c2v);
                    const unsigned k = key_of(d, code);
                    const int qi = mt * 4 + reg;
                    const unsigned mx = (q1[qi] > k) ? q1[qi] : k;
                    q2[qi] = (q2[qi] < mx) ? q2[qi] : mx;
                    q1[qi] = (q1[qi] < k) ? q1[qi] : k;
                }
            }
        }
    }

    // cross-lane top-2 reduce over the 16 code-columns (lane&15)
    #pragma unroll
    for (int off = 1; off < 16; off <<= 1) {
        #pragma unroll
        for (int qi = 0; qi < 8; ++qi) {
            const unsigned o1 = (unsigned)__shfl_xor((int)q1[qi], off);
            const unsigned o2 = (unsigned)__shfl_xor((int)q2[qi], off);
            const unsigned mx = (q1[qi] > o1) ? q1[qi] : o1;
            unsigned n2 = (q2[qi] < o2) ? q2[qi] : o2;
            n2 = (n2 < mx) ? n2 : mx;
            q1[qi] = (q1[qi] < o1) ? q1[qi] : o1;
            q2[qi] = n2;
        }
    }
    if ((lane & 15) == 0) {
        #pragma unroll
        for (int qi = 0; qi < 8; ++qi) {
            const int mt = qi >> 2, reg = qi & 3;
            const int row = (rowgrp * 2 + mt) * 16 + (lane >> 4) * 4 + reg;
            q1s[codegrp][row] = q1[qi];
            q2s[codegrp][row] = q2[qi];
        }
    }
    __syncthreads();
    if (tid < 64) {
        const unsigned a1 = q1s[0][tid], a2 = q2s[0][tid];
        const unsigned b1 = q1s[1][tid], b2 = q2s[1][tid];
        const unsigned q1f = (a1 < b1) ? a1 : b1;
        const unsigned mx = (a1 > b1) ? a1 : b1;
        unsigned q2f = (a2 < b2) ? a2 : b2;
        q2f = (q2f < mx) ? q2f : mx;
        const int idx = (int)(q1f & 1023u);
        const int grow = bh * 64 + tid;
        idx_int[grow] = idx;
        out[IDX_OFF + grow] = (float)idx;
        const float d1 = key_val(q1f), d2 = key_val(q2f);
        if (d2 - d1 < 0.5f) {               // tight gap -> exact fp32 rescore
            const int pos = atomicAdd(cnt, 1);
            rows[pos] = grow;
        }
    }
}

// ---------------------------------------------------------------------------
// Fixup: exact fp32 full-scan argmin for flagged rows (round-1 numerics).
__global__ __launch_bounds__(256) void fixup(const float* __restrict__ x,
                                             const float* __restrict__ cb,
                                             const float* __restrict__ c2,
                                             const int* __restrict__ cnt,
                                             const int* __restrict__ rows,
                                             float* __restrict__ out,
                                             int* __restrict__ idx_int) {
    __shared__ float xs[256];
    __shared__ float ds[256];
    __shared__ int kk[256];
    const int t = threadIdx.x;
    const int n = cnt[0];
    for (int i = blockIdx.x; i < n; i += gridDim.x) {
        const int row = rows[i];
        const int b = row >> 12, h = (row >> 6) & 63, w = row & 63;
        __syncthreads();
        xs[t] = x[(((size_t)b * Cd + t) * Hn + h) * Wn + w];
        __syncthreads();
        float bd = 3.4e38f; int bk = 0;
        for (int j = 0; j < 4; ++j) {
            const int k = t * 4 + j;
            float dot = 0.f;
            for (int c = 0; c < Cd; ++c) dot = fmaf(xs[c], cb[(size_t)k * Cd + c], dot);
            const float d = c2[k] - 2.f * dot;
            if (d < bd) { bd = d; bk = k; }
        }
        ds[t] = bd; kk[t] = bk;
        __syncthreads();
        for (int s = 128; s > 0; s >>= 1) {
            if (t < s) {
                const float od = ds[t + s]; const int ok = kk[t + s];
                if (od < ds[t] || (od == ds[t] && ok < kk[t])) { ds[t] = od; kk[t] = ok; }
            }
            __syncthreads();
        }
        if (t == 0) { idx_int[row] = kk[0]; out[IDX_OFF + row] = (float)kk[0]; }
    }
}

// ---------------------------------------------------------------------------
// Epilogue: gather quant, transposed coalesced write, losses.
__global__ __launch_bounds__(256) void epilogue(const float* __restrict__ x,
                                                const float* __restrict__ cb,
                                                const int* __restrict__ idx_int,
                                                float* __restrict__ out) {
    __shared__ int idx_s[64];
    __shared__ float red[4];
    const int tid = threadIdx.x;
    const int bh = blockIdx.x;
    const int b = bh >> 6, h = bh & 63;
    if (tid < 64) idx_s[tid] = idx_int[bh * 64 + tid];
    __syncthreads();
    const int w = tid & 63, cq = tid >> 6;
    const int myidx = idx_s[w];
    float lsum = 0.f;
    for (int c = cq; c < Cd; c += 4) {
        const float qv = cb[(size_t)myidx * Cd + c];
        const size_t o = (((size_t)b * Cd + c) * Hn + h) * Wn + w;
        const float xv = x[o];
        const float dd = qv - xv;
        lsum += dd * dd;
        out[o] = qv;
    }
    #pragma unroll
    for (int off = 32; off >= 1; off >>= 1) lsum += __shfl_xor(lsum, off);
    if ((tid & 63) == 0) red[tid >> 6] = lsum;
    __syncthreads();
    if (tid == 0) {
        const float s = (red[0] + red[1] + red[2] + red[3]) * (1.0f / 16777216.0f);
        atomicAdd(out + LOSS_OFF, s);
        atomicAdd(out + LOSS_OFF + 1, s);
    }
}

// ---------------------------------------------------------------------------
extern "C" void kernel_launch(void* const* d_in, const int* in_sizes, int n_in,
                              void* d_out, int out_size, void* d_ws, size_t ws_size,
                              hipStream_t stream) {
    const float* x  = (const float*)d_in[0];   // (16,256,64,64)
    const float* cb = (const float*)d_in[1];   // (1024,256)
    float* out = (float*)d_out;
    char* ws = (char*)d_ws;
    _Float16* cbFh = (_Float16*)(ws + WS_CBFH);
    _Float16* cbFl = (_Float16*)(ws + WS_CBFL);
    float* c2      = (float*)(ws + WS_C2);
    int* cnt       = (int*)(ws + WS_CNT);
    int* rows      = (int*)(ws + WS_ROWS);
    int* idx_int   = (int*)(ws + WS_IDX);

    cb_frag<<<128, 256, 0, stream>>>(cb, cbFh, cbFl, cnt);
    c2_kernel<<<256, 256, 0, stream>>>(cb, c2, out);
    vq_main<<<Bn * Hn, 256, 0, stream>>>(x, cbFh, cbFl, c2, out, idx_int, cnt, rows);
    fixup<<<128, 256, 0, stream>>>(x, cb, c2, cnt, rows, out, idx_int);
    epilogue<<<Bn * Hn, 256, 0, stream>>>(x, cb, idx_int, out);
}

// Round 3
// 787.633 us; speedup vs baseline: 1.2542x; 1.2542x over previous
//
#include <hip/hip_runtime.h>

// Problem constants
constexpr int Bn = 16, Cd = 256, Hn = 64, Wn = 64, Kc = 1024;
constexpr int QUANT_ELEMS = Bn * Hn * Wn * Cd;   // 16777216
constexpr int LOSS_OFF = QUANT_ELEMS;            // +0 codebook_loss, +1 commitment_loss
constexpr int IDX_OFF = QUANT_ELEMS + 2;         // 65536 indices (stored as float)

typedef _Float16 half8 __attribute__((ext_vector_type(8)));
typedef float f32x4 __attribute__((ext_vector_type(4)));

// ws layout (bytes):
constexpr size_t WS_CBFH = 0;
constexpr size_t WS_CBFL = 512 * 1024;
constexpr size_t WS_C2   = 1024 * 1024;
constexpr size_t WS_CNT  = 1024 * 1024 + 4096;
constexpr size_t WS_ROWS = 1024 * 1024 + 8192;
constexpr size_t WS_IDX  = 1024 * 1024 + 8192 + 262144;

// Sortable-uint key helpers: monotone in float value, idx in low 10 bits.
__device__ __forceinline__ unsigned key_of(float d, int code) {
    unsigned u = __float_as_uint(d);
    u ^= (unsigned)((int)u >> 31) | 0x80000000u;
    return (u & 0xFFFFFC00u) | (unsigned)code;
}
__device__ __forceinline__ float key_val(unsigned k) {
    unsigned u = k & 0xFFFFFC00u;
    u ^= (u & 0x80000000u) ? 0x80000000u : 0xFFFFFFFFu;
    return __uint_as_float(u);
}

// ---------------------------------------------------------------------------
// Prep: split codebook into fp16 hi/lo in MFMA B-fragment-linear layout.
__global__ __launch_bounds__(256) void cb_frag(const float* __restrict__ cb,
                                               _Float16* __restrict__ cbFh,
                                               _Float16* __restrict__ cbFl,
                                               int* __restrict__ cnt) {
    const int e = blockIdx.x * 256 + threadIdx.x;   // 32768 entries
    const int ntile = e >> 9;
    const int kblk = (e >> 6) & 7;
    const int l = e & 63;
    const int code = ntile * 16 + (l & 15);
    const int cbase = kblk * 32 + (l >> 4) * 8;
    half8 hh, ll;
    #pragma unroll
    for (int j = 0; j < 8; ++j) {
        const float v = cb[(size_t)code * Cd + cbase + j];
        const _Float16 h = (_Float16)v;
        hh[j] = h;
        ll[j] = (_Float16)(v - (float)h);
    }
    *(half8*)(cbFh + (size_t)e * 8) = hh;
    *(half8*)(cbFl + (size_t)e * 8) = ll;
    if (e == 0) cnt[0] = 0;
}

// c2[k] = ||codebook_k||^2 + zero the loss outputs.
__global__ __launch_bounds__(256) void c2_kernel(const float* __restrict__ cb,
                                                 float* __restrict__ c2,
                                                 float* __restrict__ out) {
    const int tid = threadIdx.x;
    const int k = blockIdx.x * 4 + (tid >> 6);
    const int lane = tid & 63;
    float s = 0.f;
    #pragma unroll
    for (int j = 0; j < 4; ++j) {
        const float v = cb[(size_t)k * Cd + lane + 64 * j];
        s += v * v;
    }
    #pragma unroll
    for (int off = 32; off >= 1; off >>= 1) s += __shfl_xor(s, off);
    if (lane == 0) c2[k] = s;
    if (blockIdx.x == 0 && tid == 0) { out[LOSS_OFF] = 0.f; out[LOSS_OFF + 1] = 0.f; }
}

// ---------------------------------------------------------------------------
// Main MFMA kernel — UNCHANGED from round 2 (passed correctness).
__global__ __launch_bounds__(256, 2) void vq_main(const float* __restrict__ x,
                                                  const _Float16* __restrict__ cbFh,
                                                  const _Float16* __restrict__ cbFl,
                                                  const float* __restrict__ c2,
                                                  float* __restrict__ out,
                                                  int* __restrict__ idx_int,
                                                  int* __restrict__ cnt,
                                                  int* __restrict__ rows) {
    __shared__ float4 Aimg[1024];      // 16 KB: [sub(2)][gmt(4)][plane(2)][lane(64)]
    __shared__ unsigned q1s[2][64], q2s[2][64];

    const int tid = threadIdx.x;
    const int lane = tid & 63;
    const int wv = tid >> 6;
    const int rowgrp = wv >> 1;
    const int codegrp = wv & 1;
    const int bh = blockIdx.x;
    const int b = bh >> 6, h = bh & 63;

    const int s_rowq = tid & 15;
    const int s_cq = tid >> 4;

    unsigned q1[8], q2[8];
    #pragma unroll
    for (int i = 0; i < 8; ++i) { q1[i] = 0xFFFFFFFFu; q2[i] = 0xFFFFFFFFu; }

    for (int sweep = 0; sweep < 4; ++sweep) {
        f32x4 acc[2][8];
        #pragma unroll
        for (int mt = 0; mt < 2; ++mt)
            #pragma unroll
            for (int nt = 0; nt < 8; ++nt) acc[mt][nt] = (f32x4){0.f, 0.f, 0.f, 0.f};

        for (int chunk = 0; chunk < 4; ++chunk) {
            const int c0 = chunk * 64;
            __syncthreads();
            {   // stage A: 64 rows x 64 c fp32, transposed to fragment-linear
                const int w0 = s_rowq * 4;
                const int cc = s_cq * 4;
                float4 f4[4];
                #pragma unroll
                for (int i = 0; i < 4; ++i)
                    f4[i] = *(const float4*)&x[(((size_t)b * Cd + c0 + cc + i) * Hn + h) * Wn + w0];
                const int sub = cc >> 5;
                const int cr = cc & 31;
                const int g = cr >> 3;
                const int plane = (cr >> 2) & 1;
                #pragma unroll
                for (int r = 0; r < 4; ++r) {
                    const int m = w0 + r;
                    const int gmt = m >> 4, m15 = m & 15;
                    float4 ent;
                    const float* fp = (const float*)f4;
                    ent.x = fp[0 * 4 + r]; ent.y = fp[1 * 4 + r];
                    ent.z = fp[2 * 4 + r]; ent.w = fp[3 * 4 + r];
                    Aimg[((sub * 4 + gmt) * 2 + plane) * 64 + ((g << 4) | m15)] = ent;
                }
            }
            __syncthreads();

            for (int ks = 0; ks < 2; ++ks) {
                const int kblk = chunk * 2 + ks;
                half8 bhf[8], blf[8];
                #pragma unroll
                for (int nt = 0; nt < 8; ++nt) {
                    const int ntile = sweep * 16 + codegrp * 8 + nt;
                    const size_t be = ((size_t)(ntile * 8 + kblk) * 64 + lane) * 8;
                    bhf[nt] = *(const half8*)(cbFh + be);
                    blf[nt] = *(const half8*)(cbFl + be);
                }
                half8 ahf[2], alf[2];
                #pragma unroll
                for (int mt = 0; mt < 2; ++mt) {
                    const int base = ((ks * 4 + rowgrp * 2 + mt) * 2) * 64 + lane;
                    const float4 p0 = Aimg[base];
                    const float4 p1 = Aimg[base + 64];
                    const float av[8] = {p0.x, p0.y, p0.z, p0.w, p1.x, p1.y, p1.z, p1.w};
                    #pragma unroll
                    for (int j = 0; j < 8; ++j) {
                        const _Float16 hh = (_Float16)av[j];
                        ahf[mt][j] = hh;
                        alf[mt][j] = (_Float16)(av[j] - (float)hh);
                    }
                }
                #pragma unroll
                for (int nt = 0; nt < 8; ++nt)
                    #pragma unroll
                    for (int mt = 0; mt < 2; ++mt)
                        acc[mt][nt] = __builtin_amdgcn_mfma_f32_16x16x32_f16(ahf[mt], bhf[nt], acc[mt][nt], 0, 0, 0);
                #pragma unroll
                for (int nt = 0; nt < 8; ++nt)
                    #pragma unroll
                    for (int mt = 0; mt < 2; ++mt)
                        acc[mt][nt] = __builtin_amdgcn_mfma_f32_16x16x32_f16(ahf[mt], blf[nt], acc[mt][nt], 0, 0, 0);
                #pragma unroll
                for (int nt = 0; nt < 8; ++nt)
                    #pragma unroll
                    for (int mt = 0; mt < 2; ++mt)
                        acc[mt][nt] = __builtin_amdgcn_mfma_f32_16x16x32_f16(alf[mt], bhf[nt], acc[mt][nt], 0, 0, 0);
            }
        }

        #pragma unroll
        for (int nt = 0; nt < 8; ++nt) {
            const int ntile = sweep * 16 + codegrp * 8 + nt;
            const int code = ntile * 16 + (lane & 15);
            const float c2v = c2[code];
            #pragma unroll
            for (int mt = 0; mt < 2; ++mt) {
                #pragma unroll
                for (int reg = 0; reg < 4; ++reg) {
                    const float d = fmaf(-2.f, acc[mt][nt][reg], c2v);
                    const unsigned k = key_of(d, code);
                    const int qi = mt * 4 + reg;
                    const unsigned mx = (q1[qi] > k) ? q1[qi] : k;
                    q2[qi] = (q2[qi] < mx) ? q2[qi] : mx;
                    q1[qi] = (q1[qi] < k) ? q1[qi] : k;
                }
            }
        }
    }

    #pragma unroll
    for (int off = 1; off < 16; off <<= 1) {
        #pragma unroll
        for (int qi = 0; qi < 8; ++qi) {
            const unsigned o1 = (unsigned)__shfl_xor((int)q1[qi], off);
            const unsigned o2 = (unsigned)__shfl_xor((int)q2[qi], off);
            const unsigned mx = (q1[qi] > o1) ? q1[qi] : o1;
            unsigned n2 = (q2[qi] < o2) ? q2[qi] : o2;
            n2 = (n2 < mx) ? n2 : mx;
            q1[qi] = (q1[qi] < o1) ? q1[qi] : o1;
            q2[qi] = n2;
        }
    }
    if ((lane & 15) == 0) {
        #pragma unroll
        for (int qi = 0; qi < 8; ++qi) {
            const int mt = qi >> 2, reg = qi & 3;
            const int row = (rowgrp * 2 + mt) * 16 + (lane >> 4) * 4 + reg;
            q1s[codegrp][row] = q1[qi];
            q2s[codegrp][row] = q2[qi];
        }
    }
    __syncthreads();
    if (tid < 64) {
        const unsigned a1 = q1s[0][tid], a2 = q2s[0][tid];
        const unsigned b1 = q1s[1][tid], b2 = q2s[1][tid];
        const unsigned q1f = (a1 < b1) ? a1 : b1;
        const unsigned mx = (a1 > b1) ? a1 : b1;
        unsigned q2f = (a2 < b2) ? a2 : b2;
        q2f = (q2f < mx) ? q2f : mx;
        const int idx = (int)(q1f & 1023u);
        const int grow = bh * 64 + tid;
        idx_int[grow] = idx;
        out[IDX_OFF + grow] = (float)idx;
        const float d1 = key_val(q1f), d2 = key_val(q2f);
        if (d2 - d1 < 0.5f) {
            const int pos = atomicAdd(cnt, 1);
            rows[pos] = grow;
        }
    }
}

// ---------------------------------------------------------------------------
// Fixup v2: exact fp32 full-scan argmin for flagged rows.
// One row per block per grid-stride step; float4 codebook loads; 4 independent
// code accumulator chains per thread for ILP. cb (1 MB) stays L2-resident.
__global__ __launch_bounds__(256) void fixup(const float* __restrict__ x,
                                             const float* __restrict__ cb,
                                             const float* __restrict__ c2,
                                             const int* __restrict__ cnt,
                                             const int* __restrict__ rows,
                                             float* __restrict__ out,
                                             int* __restrict__ idx_int) {
    __shared__ float xs[256];
    __shared__ float ds[256];
    __shared__ int kk[256];
    const int t = threadIdx.x;
    const int n = cnt[0];
    for (int i = blockIdx.x; i < n; i += gridDim.x) {
        const int row = rows[i];
        const int b = row >> 12, h = (row >> 6) & 63, w = row & 63;
        __syncthreads();
        xs[t] = x[(((size_t)b * Cd + t) * Hn + h) * Wn + w];
        __syncthreads();
        // Thread t scores codes t*4 .. t*4+3 (4 independent fma chains).
        const float4* xv4 = (const float4*)xs;
        float dot[4] = {0.f, 0.f, 0.f, 0.f};
        const float4* cbp0 = (const float4*)(cb + (size_t)(t * 4 + 0) * Cd);
        const float4* cbp1 = (const float4*)(cb + (size_t)(t * 4 + 1) * Cd);
        const float4* cbp2 = (const float4*)(cb + (size_t)(t * 4 + 2) * Cd);
        const float4* cbp3 = (const float4*)(cb + (size_t)(t * 4 + 3) * Cd);
        #pragma unroll 8
        for (int c4 = 0; c4 < 64; ++c4) {
            const float4 xv = xv4[c4];
            const float4 v0 = cbp0[c4];
            const float4 v1 = cbp1[c4];
            const float4 v2 = cbp2[c4];
            const float4 v3 = cbp3[c4];
            dot[0] = fmaf(v0.x, xv.x, dot[0]); dot[0] = fmaf(v0.y, xv.y, dot[0]);
            dot[0] = fmaf(v0.z, xv.z, dot[0]); dot[0] = fmaf(v0.w, xv.w, dot[0]);
            dot[1] = fmaf(v1.x, xv.x, dot[1]); dot[1] = fmaf(v1.y, xv.y, dot[1]);
            dot[1] = fmaf(v1.z, xv.z, dot[1]); dot[1] = fmaf(v1.w, xv.w, dot[1]);
            dot[2] = fmaf(v2.x, xv.x, dot[2]); dot[2] = fmaf(v2.y, xv.y, dot[2]);
            dot[2] = fmaf(v2.z, xv.z, dot[2]); dot[2] = fmaf(v2.w, xv.w, dot[2]);
            dot[3] = fmaf(v3.x, xv.x, dot[3]); dot[3] = fmaf(v3.y, xv.y, dot[3]);
            dot[3] = fmaf(v3.z, xv.z, dot[3]); dot[3] = fmaf(v3.w, xv.w, dot[3]);
        }
        float bd = 3.4e38f; int bk = 0;
        #pragma unroll
        for (int j = 0; j < 4; ++j) {
            const int k = t * 4 + j;
            const float d = c2[k] - 2.f * dot[j];
            if (d < bd) { bd = d; bk = k; }   // ascending k -> lowest-k tie-break
        }
        ds[t] = bd; kk[t] = bk;
        __syncthreads();
        for (int s = 128; s > 0; s >>= 1) {
            if (t < s) {
                const float od = ds[t + s]; const int ok = kk[t + s];
                if (od < ds[t] || (od == ds[t] && ok < kk[t])) { ds[t] = od; kk[t] = ok; }
            }
            __syncthreads();
        }
        if (t == 0) { idx_int[row] = kk[0]; out[IDX_OFF + row] = (float)kk[0]; }
    }
}

// ---------------------------------------------------------------------------
// Epilogue: gather quant, transposed coalesced write, losses.
__global__ __launch_bounds__(256) void epilogue(const float* __restrict__ x,
                                                const float* __restrict__ cb,
                                                const int* __restrict__ idx_int,
                                                float* __restrict__ out) {
    __shared__ int idx_s[64];
    __shared__ float red[4];
    const int tid = threadIdx.x;
    const int bh = blockIdx.x;
    const int b = bh >> 6, h = bh & 63;
    if (tid < 64) idx_s[tid] = idx_int[bh * 64 + tid];
    __syncthreads();
    const int w = tid & 63, cq = tid >> 6;
    const int myidx = idx_s[w];
    float lsum = 0.f;
    for (int c = cq; c < Cd; c += 4) {
        const float qv = cb[(size_t)myidx * Cd + c];
        const size_t o = (((size_t)b * Cd + c) * Hn + h) * Wn + w;
        const float xv = x[o];
        const float dd = qv - xv;
        lsum += dd * dd;
        out[o] = qv;
    }
    #pragma unroll
    for (int off = 32; off >= 1; off >>= 1) lsum += __shfl_xor(lsum, off);
    if ((tid & 63) == 0) red[tid >> 6] = lsum;
    __syncthreads();
    if (tid == 0) {
        const float s = (red[0] + red[1] + red[2] + red[3]) * (1.0f / 16777216.0f);
        atomicAdd(out + LOSS_OFF, s);
        atomicAdd(out + LOSS_OFF + 1, s);
    }
}

// ---------------------------------------------------------------------------
extern "C" void kernel_launch(void* const* d_in, const int* in_sizes, int n_in,
                              void* d_out, int out_size, void* d_ws, size_t ws_size,
                              hipStream_t stream) {
    const float* x  = (const float*)d_in[0];   // (16,256,64,64)
    const float* cb = (const float*)d_in[1];   // (1024,256)
    float* out = (float*)d_out;
    char* ws = (char*)d_ws;
    _Float16* cbFh = (_Float16*)(ws + WS_CBFH);
    _Float16* cbFl = (_Float16*)(ws + WS_CBFL);
    float* c2      = (float*)(ws + WS_C2);
    int* cnt       = (int*)(ws + WS_CNT);
    int* rows      = (int*)(ws + WS_ROWS);
    int* idx_int   = (int*)(ws + WS_IDX);

    cb_frag<<<128, 256, 0, stream>>>(cb, cbFh, cbFl, cnt);
    c2_kernel<<<256, 256, 0, stream>>>(cb, c2, out);
    vq_main<<<Bn * Hn, 256, 0, stream>>>(x, cbFh, cbFl, c2, out, idx_int, cnt, rows);
    fixup<<<256, 256, 0, stream>>>(x, cb, c2, cnt, rows, out, idx_int);
    epilogue<<<Bn * Hn, 256, 0, stream>>>(x, cb, idx_int, out);
}

// Round 4
// 366.168 us; speedup vs baseline: 2.6978x; 2.1510x over previous
//
#include <hip/hip_runtime.h>

// Problem constants
constexpr int Bn = 16, Cd = 256, Hn = 64, Wn = 64, Kc = 1024;
constexpr int QUANT_ELEMS = Bn * Hn * Wn * Cd;   // 16777216
constexpr int LOSS_OFF = QUANT_ELEMS;            // +0 codebook_loss, +1 commitment_loss
constexpr int IDX_OFF = QUANT_ELEMS + 2;         // 65536 indices (stored as float)

typedef _Float16 half8 __attribute__((ext_vector_type(8)));
typedef float f32x4 __attribute__((ext_vector_type(4)));

// ws layout (bytes):
constexpr size_t WS_CBFH = 0;                            // 512 KB fp16 hi codebook (B-frag)
constexpr size_t WS_CBFL = 512 * 1024;                   // 512 KB fp16 lo residual
constexpr size_t WS_C2   = 1024 * 1024;                  // 4 KB
constexpr size_t WS_CNT  = 1024 * 1024 + 4096;           // 4 B flagged count
constexpr size_t WS_ROWS = 1024 * 1024 + 8192;           // 256 KB flagged rows
constexpr size_t WS_IDX  = 1024 * 1024 + 8192 + 262144;  // 256 KB final int idx
constexpr size_t WS_CBT  = 1024 * 1024 + 8192 + 524288;  // 1 MB cbT (C,K) fp32

// ---------------------------------------------------------------------------
// Prep 0: transpose codebook (K,C) -> cbT (C,K) for the coalesced exact fixup.
__global__ __launch_bounds__(256) void transpose_cb(const float* __restrict__ cb,
                                                    float* __restrict__ cbT) {
    __shared__ float t[64][65];
    const int tid = threadIdx.x;
    const int k0 = blockIdx.x * 64;
    const int c0 = blockIdx.y * 64;
    {
        const int c = tid & 63, i0 = tid >> 6;
        for (int i = i0; i < 64; i += 4)
            t[i][c] = cb[(size_t)(k0 + i) * Cd + c0 + c];
    }
    __syncthreads();
    {
        const int kk = tid & 63, j0 = tid >> 6;
        for (int j = j0; j < 64; j += 4)
            cbT[(size_t)(c0 + j) * Kc + k0 + kk] = t[kk][j];
    }
}

// Prep 1: split codebook into fp16 hi/lo in MFMA B-fragment-linear layout.
__global__ __launch_bounds__(256) void cb_frag(const float* __restrict__ cb,
                                               _Float16* __restrict__ cbFh,
                                               _Float16* __restrict__ cbFl,
                                               int* __restrict__ cnt) {
    const int e = blockIdx.x * 256 + threadIdx.x;   // 32768 entries
    const int ntile = e >> 9;
    const int kblk = (e >> 6) & 7;
    const int l = e & 63;
    const int code = ntile * 16 + (l & 15);
    const int cbase = kblk * 32 + (l >> 4) * 8;
    half8 hh, ll;
    #pragma unroll
    for (int j = 0; j < 8; ++j) {
        const float v = cb[(size_t)code * Cd + cbase + j];
        const _Float16 h = (_Float16)v;
        hh[j] = h;
        ll[j] = (_Float16)(v - (float)h);
    }
    *(half8*)(cbFh + (size_t)e * 8) = hh;
    *(half8*)(cbFl + (size_t)e * 8) = ll;
    if (e == 0) cnt[0] = 0;
}

// Prep 2: c2[k] = ||codebook_k||^2 + zero the loss outputs.
__global__ __launch_bounds__(256) void c2_kernel(const float* __restrict__ cb,
                                                 float* __restrict__ c2,
                                                 float* __restrict__ out) {
    const int tid = threadIdx.x;
    const int k = blockIdx.x * 4 + (tid >> 6);
    const int lane = tid & 63;
    float s = 0.f;
    #pragma unroll
    for (int j = 0; j < 4; ++j) {
        const float v = cb[(size_t)k * Cd + lane + 64 * j];
        s += v * v;
    }
    #pragma unroll
    for (int off = 32; off >= 1; off >>= 1) s += __shfl_xor(s, off);
    if (lane == 0) c2[k] = s;
    if (blockIdx.x == 0 && tid == 0) { out[LOSS_OFF] = 0.f; out[LOSS_OFF + 1] = 0.f; }
}

// ---------------------------------------------------------------------------
// Main MFMA kernel. MFMA core + staging identical to rounds 2/3 (passed).
// Changed: argmin tracking uses exact (d1, i1, d2) triples instead of
// quantized 22-bit keys -> flag threshold drops 0.5 -> 0.05, ~10x fewer flags.
__global__ __launch_bounds__(256, 2) void vq_main(const float* __restrict__ x,
                                                  const _Float16* __restrict__ cbFh,
                                                  const _Float16* __restrict__ cbFl,
                                                  const float* __restrict__ c2,
                                                  float* __restrict__ out,
                                                  int* __restrict__ idx_int,
                                                  int* __restrict__ cnt,
                                                  int* __restrict__ rows) {
    __shared__ float4 Aimg[1024];      // 16 KB: [sub(2)][gmt(4)][plane(2)][lane(64)]
    __shared__ float q1ds[2][64];
    __shared__ int   q1is[2][64];
    __shared__ float q2ds[2][64];

    const int tid = threadIdx.x;
    const int lane = tid & 63;
    const int wv = tid >> 6;
    const int rowgrp = wv >> 1;
    const int codegrp = wv & 1;
    const int bh = blockIdx.x;
    const int b = bh >> 6, h = bh & 63;

    const int s_rowq = tid & 15;
    const int s_cq = tid >> 4;

    float q1d[8], q2d[8];
    int   q1i[8];
    #pragma unroll
    for (int i = 0; i < 8; ++i) { q1d[i] = 3.4e38f; q2d[i] = 3.4e38f; q1i[i] = 0; }

    for (int sweep = 0; sweep < 4; ++sweep) {
        f32x4 acc[2][8];
        #pragma unroll
        for (int mt = 0; mt < 2; ++mt)
            #pragma unroll
            for (int nt = 0; nt < 8; ++nt) acc[mt][nt] = (f32x4){0.f, 0.f, 0.f, 0.f};

        for (int chunk = 0; chunk < 4; ++chunk) {
            const int c0 = chunk * 64;
            __syncthreads();
            {   // stage A: 64 rows x 64 c fp32, transposed to fragment-linear
                const int w0 = s_rowq * 4;
                const int cc = s_cq * 4;
                float4 f4[4];
                #pragma unroll
                for (int i = 0; i < 4; ++i)
                    f4[i] = *(const float4*)&x[(((size_t)b * Cd + c0 + cc + i) * Hn + h) * Wn + w0];
                const int sub = cc >> 5;
                const int cr = cc & 31;
                const int g = cr >> 3;
                const int plane = (cr >> 2) & 1;
                #pragma unroll
                for (int r = 0; r < 4; ++r) {
                    const int m = w0 + r;
                    const int gmt = m >> 4, m15 = m & 15;
                    float4 ent;
                    const float* fp = (const float*)f4;
                    ent.x = fp[0 * 4 + r]; ent.y = fp[1 * 4 + r];
                    ent.z = fp[2 * 4 + r]; ent.w = fp[3 * 4 + r];
                    Aimg[((sub * 4 + gmt) * 2 + plane) * 64 + ((g << 4) | m15)] = ent;
                }
            }
            __syncthreads();

            for (int ks = 0; ks < 2; ++ks) {
                const int kblk = chunk * 2 + ks;
                half8 bhf[8], blf[8];
                #pragma unroll
                for (int nt = 0; nt < 8; ++nt) {
                    const int ntile = sweep * 16 + codegrp * 8 + nt;
                    const size_t be = ((size_t)(ntile * 8 + kblk) * 64 + lane) * 8;
                    bhf[nt] = *(const half8*)(cbFh + be);
                    blf[nt] = *(const half8*)(cbFl + be);
                }
                half8 ahf[2], alf[2];
                #pragma unroll
                for (int mt = 0; mt < 2; ++mt) {
                    const int base = ((ks * 4 + rowgrp * 2 + mt) * 2) * 64 + lane;
                    const float4 p0 = Aimg[base];
                    const float4 p1 = Aimg[base + 64];
                    const float av[8] = {p0.x, p0.y, p0.z, p0.w, p1.x, p1.y, p1.z, p1.w};
                    #pragma unroll
                    for (int j = 0; j < 8; ++j) {
                        const _Float16 hh = (_Float16)av[j];
                        ahf[mt][j] = hh;
                        alf[mt][j] = (_Float16)(av[j] - (float)hh);
                    }
                }
                #pragma unroll
                for (int nt = 0; nt < 8; ++nt)
                    #pragma unroll
                    for (int mt = 0; mt < 2; ++mt)
                        acc[mt][nt] = __builtin_amdgcn_mfma_f32_16x16x32_f16(ahf[mt], bhf[nt], acc[mt][nt], 0, 0, 0);
                #pragma unroll
                for (int nt = 0; nt < 8; ++nt)
                    #pragma unroll
                    for (int mt = 0; mt < 2; ++mt)
                        acc[mt][nt] = __builtin_amdgcn_mfma_f32_16x16x32_f16(ahf[mt], blf[nt], acc[mt][nt], 0, 0, 0);
                #pragma unroll
                for (int nt = 0; nt < 8; ++nt)
                    #pragma unroll
                    for (int mt = 0; mt < 2; ++mt)
                        acc[mt][nt] = __builtin_amdgcn_mfma_f32_16x16x32_f16(alf[mt], bhf[nt], acc[mt][nt], 0, 0, 0);
            }
        }

        // fold sweep's 256 codes into per-row exact top-2
        #pragma unroll
        for (int nt = 0; nt < 8; ++nt) {
            const int ntile = sweep * 16 + codegrp * 8 + nt;
            const int code = ntile * 16 + (lane & 15);
            const float c2v = c2[code];
            #pragma unroll
            for (int mt = 0; mt < 2; ++mt) {
                #pragma unroll
                for (int reg = 0; reg < 4; ++reg) {
                    const float d = fmaf(-2.f, acc[mt][nt][reg], c2v);
                    const int qi = mt * 4 + reg;
                    const bool better = (d < q1d[qi]) || (d == q1d[qi] && code < q1i[qi]);
                    const float second = better ? q1d[qi] : d;
                    q2d[qi] = fminf(q2d[qi], second);
                    q1i[qi] = better ? code : q1i[qi];
                    q1d[qi] = better ? d : q1d[qi];
                }
            }
        }
    }

    // cross-lane top-2 reduce over the 16 code-columns (lane&15)
    #pragma unroll
    for (int off = 1; off < 16; off <<= 1) {
        #pragma unroll
        for (int qi = 0; qi < 8; ++qi) {
            const float od1 = __shfl_xor(q1d[qi], off);
            const int   oi1 = __shfl_xor(q1i[qi], off);
            const float od2 = __shfl_xor(q2d[qi], off);
            const bool obetter = (od1 < q1d[qi]) || (od1 == q1d[qi] && oi1 < q1i[qi]);
            const float loser = obetter ? q1d[qi] : od1;
            q2d[qi] = fminf(fminf(q2d[qi], od2), loser);
            q1d[qi] = obetter ? od1 : q1d[qi];
            q1i[qi] = obetter ? oi1 : q1i[qi];
        }
    }
    if ((lane & 15) == 0) {
        #pragma unroll
        for (int qi = 0; qi < 8; ++qi) {
            const int mt = qi >> 2, reg = qi & 3;
            const int row = (rowgrp * 2 + mt) * 16 + (lane >> 4) * 4 + reg;
            q1ds[codegrp][row] = q1d[qi];
            q1is[codegrp][row] = q1i[qi];
            q2ds[codegrp][row] = q2d[qi];
        }
    }
    __syncthreads();
    if (tid < 64) {
        const float a1 = q1ds[0][tid]; const int ai = q1is[0][tid]; const float a2 = q2ds[0][tid];
        const float b1 = q1ds[1][tid]; const int bi = q1is[1][tid]; const float b2 = q2ds[1][tid];
        const bool bbetter = (b1 < a1) || (b1 == a1 && bi < ai);
        const float d1 = bbetter ? b1 : a1;
        const int   idx = bbetter ? bi : ai;
        const float loser = bbetter ? a1 : b1;
        const float d2 = fminf(fminf(a2, b2), loser);
        const int grow = bh * 64 + tid;
        idx_int[grow] = idx;
        out[IDX_OFF + grow] = (float)idx;
        if (d2 - d1 < 0.05f) {               // tight gap -> exact fp32 rescore
            const int pos = atomicAdd(cnt, 1);
            rows[pos] = grow;
        }
    }
}

// ---------------------------------------------------------------------------
// Fixup v3: exact fp32 full-scan argmin for flagged rows, COALESCED via cbT.
// Thread t scores codes 4t..4t+3; loads cbT[c*1024 + 4t] are 16B/lane
// contiguous across the wave. cb stays L2-resident.
__global__ __launch_bounds__(256) void fixup(const float* __restrict__ x,
                                             const float* __restrict__ cbT,
                                             const float* __restrict__ c2,
                                             const int* __restrict__ cnt,
                                             const int* __restrict__ rows,
                                             float* __restrict__ out,
                                             int* __restrict__ idx_int) {
    __shared__ float xs[256];
    __shared__ float ds[256];
    __shared__ int kk[256];
    const int t = threadIdx.x;
    const int n = cnt[0];
    for (int i = blockIdx.x; i < n; i += gridDim.x) {
        const int row = rows[i];
        const int b = row >> 12, h = (row >> 6) & 63, w = row & 63;
        __syncthreads();
        xs[t] = x[(((size_t)b * Cd + t) * Hn + h) * Wn + w];
        __syncthreads();
        float dot[4] = {0.f, 0.f, 0.f, 0.f};
        #pragma unroll 8
        for (int c = 0; c < Cd; ++c) {
            const float4 v = ((const float4*)(cbT + (size_t)c * Kc))[t];
            const float xc = xs[c];
            dot[0] = fmaf(v.x, xc, dot[0]);
            dot[1] = fmaf(v.y, xc, dot[1]);
            dot[2] = fmaf(v.z, xc, dot[2]);
            dot[3] = fmaf(v.w, xc, dot[3]);
        }
        float bd = 3.4e38f; int bk = 0;
        #pragma unroll
        for (int j = 0; j < 4; ++j) {
            const int k = t * 4 + j;
            const float d = c2[k] - 2.f * dot[j];
            if (d < bd) { bd = d; bk = k; }   // ascending k -> lowest-k tie-break
        }
        ds[t] = bd; kk[t] = bk;
        __syncthreads();
        for (int s = 128; s > 0; s >>= 1) {
            if (t < s) {
                const float od = ds[t + s]; const int ok = kk[t + s];
                if (od < ds[t] || (od == ds[t] && ok < kk[t])) { ds[t] = od; kk[t] = ok; }
            }
            __syncthreads();
        }
        if (t == 0) { idx_int[row] = kk[0]; out[IDX_OFF + row] = (float)kk[0]; }
    }
}

// ---------------------------------------------------------------------------
// Epilogue: gather quant, transposed coalesced write, losses.
__global__ __launch_bounds__(256) void epilogue(const float* __restrict__ x,
                                                const float* __restrict__ cb,
                                                const int* __restrict__ idx_int,
                                                float* __restrict__ out) {
    __shared__ int idx_s[64];
    __shared__ float red[4];
    const int tid = threadIdx.x;
    const int bh = blockIdx.x;
    const int b = bh >> 6, h = bh & 63;
    if (tid < 64) idx_s[tid] = idx_int[bh * 64 + tid];
    __syncthreads();
    const int w = tid & 63, cq = tid >> 6;
    const int myidx = idx_s[w];
    float lsum = 0.f;
    for (int c = cq; c < Cd; c += 4) {
        const float qv = cb[(size_t)myidx * Cd + c];
        const size_t o = (((size_t)b * Cd + c) * Hn + h) * Wn + w;
        const float xv = x[o];
        const float dd = qv - xv;
        lsum += dd * dd;
        out[o] = qv;
    }
    #pragma unroll
    for (int off = 32; off >= 1; off >>= 1) lsum += __shfl_xor(lsum, off);
    if ((tid & 63) == 0) red[tid >> 6] = lsum;
    __syncthreads();
    if (tid == 0) {
        const float s = (red[0] + red[1] + red[2] + red[3]) * (1.0f / 16777216.0f);
        atomicAdd(out + LOSS_OFF, s);
        atomicAdd(out + LOSS_OFF + 1, s);
    }
}

// ---------------------------------------------------------------------------
extern "C" void kernel_launch(void* const* d_in, const int* in_sizes, int n_in,
                              void* d_out, int out_size, void* d_ws, size_t ws_size,
                              hipStream_t stream) {
    const float* x  = (const float*)d_in[0];   // (16,256,64,64)
    const float* cb = (const float*)d_in[1];   // (1024,256)
    float* out = (float*)d_out;
    char* ws = (char*)d_ws;
    _Float16* cbFh = (_Float16*)(ws + WS_CBFH);
    _Float16* cbFl = (_Float16*)(ws + WS_CBFL);
    float* c2      = (float*)(ws + WS_C2);
    int* cnt       = (int*)(ws + WS_CNT);
    int* rows      = (int*)(ws + WS_ROWS);
    int* idx_int   = (int*)(ws + WS_IDX);
    float* cbT     = (float*)(ws + WS_CBT);

    transpose_cb<<<dim3(16, 4), 256, 0, stream>>>(cb, cbT);
    cb_frag<<<128, 256, 0, stream>>>(cb, cbFh, cbFl, cnt);
    c2_kernel<<<256, 256, 0, stream>>>(cb, c2, out);
    vq_main<<<Bn * Hn, 256, 0, stream>>>(x, cbFh, cbFl, c2, out, idx_int, cnt, rows);
    fixup<<<256, 256, 0, stream>>>(x, cbT, c2, cnt, rows, out, idx_int);
    epilogue<<<Bn * Hn, 256, 0, stream>>>(x, cb, idx_int, out);
}

// Round 5
// 282.253 us; speedup vs baseline: 3.4999x; 1.2973x over previous
//
#include <hip/hip_runtime.h>

// Problem constants
constexpr int Bn = 16, Cd = 256, Hn = 64, Wn = 64, Kc = 1024;
constexpr int QUANT_ELEMS = Bn * Hn * Wn * Cd;   // 16777216
constexpr int LOSS_OFF = QUANT_ELEMS;            // +0 codebook_loss, +1 commitment_loss
constexpr int IDX_OFF = QUANT_ELEMS + 2;         // 65536 indices (stored as float)

typedef _Float16 half8 __attribute__((ext_vector_type(8)));
typedef float f32x4 __attribute__((ext_vector_type(4)));

// ws layout (bytes):
constexpr size_t WS_CBFH = 0;                            // 512 KB fp16 hi codebook (B-frag)
constexpr size_t WS_CBFL = 512 * 1024;                   // 512 KB fp16 lo residual
constexpr size_t WS_C2   = 1024 * 1024;                  // 4 KB
constexpr size_t WS_CNT  = 1024 * 1024 + 4096;           // 4 B flagged count
constexpr size_t WS_ROWS = 1024 * 1024 + 8192;           // 256 KB flagged rows
constexpr size_t WS_IDX  = 1024 * 1024 + 8192 + 262144;  // 256 KB final int idx
constexpr size_t WS_CBT  = 1024 * 1024 + 8192 + 524288;  // 1 MB cbT (C,K) fp32

// ---------------------------------------------------------------------------
// Prep 0: transpose codebook (K,C) -> cbT (C,K) for the coalesced exact fixup.
__global__ __launch_bounds__(256) void transpose_cb(const float* __restrict__ cb,
                                                    float* __restrict__ cbT) {
    __shared__ float t[64][65];
    const int tid = threadIdx.x;
    const int k0 = blockIdx.x * 64;
    const int c0 = blockIdx.y * 64;
    {
        const int c = tid & 63, i0 = tid >> 6;
        for (int i = i0; i < 64; i += 4)
            t[i][c] = cb[(size_t)(k0 + i) * Cd + c0 + c];
    }
    __syncthreads();
    {
        const int kk = tid & 63, j0 = tid >> 6;
        for (int j = j0; j < 64; j += 4)
            cbT[(size_t)(c0 + j) * Kc + k0 + kk] = t[kk][j];
    }
}

// Prep 1: split codebook into fp16 hi/lo in MFMA B-fragment-linear layout.
// B frag (16x16x32 f16): lane l holds B[k=(l>>4)*8+j][n=l&15], j=0..7.
__global__ __launch_bounds__(256) void cb_frag(const float* __restrict__ cb,
                                               _Float16* __restrict__ cbFh,
                                               _Float16* __restrict__ cbFl,
                                               int* __restrict__ cnt) {
    const int e = blockIdx.x * 256 + threadIdx.x;   // 32768 entries
    const int ntile = e >> 9;
    const int kblk = (e >> 6) & 7;
    const int l = e & 63;
    const int code = ntile * 16 + (l & 15);
    const int cbase = kblk * 32 + (l >> 4) * 8;
    half8 hh, ll;
    #pragma unroll
    for (int j = 0; j < 8; ++j) {
        const float v = cb[(size_t)code * Cd + cbase + j];
        const _Float16 h = (_Float16)v;
        hh[j] = h;
        ll[j] = (_Float16)(v - (float)h);
    }
    *(half8*)(cbFh + (size_t)e * 8) = hh;
    *(half8*)(cbFl + (size_t)e * 8) = ll;
    if (e == 0) cnt[0] = 0;
}

// Prep 2: c2[k] = ||codebook_k||^2 + zero the loss outputs.
__global__ __launch_bounds__(256) void c2_kernel(const float* __restrict__ cb,
                                                 float* __restrict__ c2,
                                                 float* __restrict__ out) {
    const int tid = threadIdx.x;
    const int k = blockIdx.x * 4 + (tid >> 6);
    const int lane = tid & 63;
    float s = 0.f;
    #pragma unroll
    for (int j = 0; j < 4; ++j) {
        const float v = cb[(size_t)k * Cd + lane + 64 * j];
        s += v * v;
    }
    #pragma unroll
    for (int off = 32; off >= 1; off >>= 1) s += __shfl_xor(s, off);
    if (lane == 0) c2[k] = s;
    if (blockIdx.x == 0 && tid == 0) { out[LOSS_OFF] = 0.f; out[LOSS_OFF + 1] = 0.f; }
}

// ---------------------------------------------------------------------------
// Main MFMA kernel v3. Block = one (b,h) = 64 rows x 256 c.
// Stage x ONCE: fp16 hi/lo split directly in A-fragment-linear LDS (64 KB):
//   entry e = (kblk*4 + mt)*64 + lane, lane l holds A[m=l&15][k=(l>>4)*8+j].
// Then the whole 1024-code sweep runs barrier-free: each wave owns 16 ntiles
// (256 codes) x all 4 m-tiles, in 4 groups of acc[4mt][4nt].
// Exact top-2 (d1,i1,d2) per row; gap < 0.05 -> flag for exact fixup.
__global__ __launch_bounds__(256, 2) void vq_main(const float* __restrict__ x,
                                                  const _Float16* __restrict__ cbFh,
                                                  const _Float16* __restrict__ cbFl,
                                                  const float* __restrict__ c2,
                                                  float* __restrict__ out,
                                                  int* __restrict__ idx_int,
                                                  int* __restrict__ cnt,
                                                  int* __restrict__ rows) {
    __shared__ half8 Axh[2048];   // 32 KB: [kblk 8][mt 4][lane 64]
    __shared__ half8 Axl[2048];   // 32 KB
    __shared__ float q1ds[4][64];
    __shared__ int   q1is[4][64];
    __shared__ float q2ds[4][64];

    const int tid = threadIdx.x;
    const int lane = tid & 63;
    const int wv = tid >> 6;
    const int bh = blockIdx.x;
    const int b = bh >> 6, h = bh & 63;

    // ---- Stage x-tile once: gather + fp16 split + lane-contiguous b128 writes
    {
        const int m = tid & 15;           // row within m-tile
        const int q = (tid >> 4) & 3;     // k-quad
        const int mt = tid >> 6;          // m-tile
        const int w = mt * 16 + m;
        const float* xb = x + ((size_t)b * Cd * Hn + h) * Wn + w;   // + c*4096
        #pragma unroll
        for (int kblk = 0; kblk < 8; ++kblk) {
            half8 hv, lv;
            #pragma unroll
            for (int j = 0; j < 8; ++j) {
                const int c = kblk * 32 + q * 8 + j;
                const float v = xb[(size_t)c * (Hn * Wn)];
                const _Float16 hh = (_Float16)v;
                hv[j] = hh;
                lv[j] = (_Float16)(v - (float)hh);
            }
            const int e = (kblk * 4 + mt) * 64 + (q * 16 + m);   // == ...*64 + lane
            Axh[e] = hv;
            Axl[e] = lv;
        }
    }
    __syncthreads();

    float q1d[16], q2d[16];
    int   q1i[16];
    #pragma unroll
    for (int i = 0; i < 16; ++i) { q1d[i] = 3.4e38f; q2d[i] = 3.4e38f; q1i[i] = 0; }

    #pragma unroll 1
    for (int grp = 0; grp < 4; ++grp) {
        f32x4 acc[4][4];   // [mt][nt]
        #pragma unroll
        for (int mt = 0; mt < 4; ++mt)
            #pragma unroll
            for (int nt = 0; nt < 4; ++nt) acc[mt][nt] = (f32x4){0.f, 0.f, 0.f, 0.f};

        #pragma unroll 2
        for (int kblk = 0; kblk < 8; ++kblk) {
            half8 bhf[4], blf[4];
            #pragma unroll
            for (int nt = 0; nt < 4; ++nt) {
                const int ntile = wv * 16 + grp * 4 + nt;
                const size_t be = ((size_t)(ntile * 8 + kblk) * 64 + lane) * 8;
                bhf[nt] = *(const half8*)(cbFh + be);
                blf[nt] = *(const half8*)(cbFl + be);
            }
            half8 ahf[4], alf[4];
            #pragma unroll
            for (int mt = 0; mt < 4; ++mt) {
                const int e = (kblk * 4 + mt) * 64 + lane;
                ahf[mt] = Axh[e];
                alf[mt] = Axl[e];
            }
            // 3 terms (hh, hl, lh); dependent MFMAs on same acc spaced 16 apart
            #pragma unroll
            for (int nt = 0; nt < 4; ++nt)
                #pragma unroll
                for (int mt = 0; mt < 4; ++mt)
                    acc[mt][nt] = __builtin_amdgcn_mfma_f32_16x16x32_f16(ahf[mt], bhf[nt], acc[mt][nt], 0, 0, 0);
            #pragma unroll
            for (int nt = 0; nt < 4; ++nt)
                #pragma unroll
                for (int mt = 0; mt < 4; ++mt)
                    acc[mt][nt] = __builtin_amdgcn_mfma_f32_16x16x32_f16(ahf[mt], blf[nt], acc[mt][nt], 0, 0, 0);
            #pragma unroll
            for (int nt = 0; nt < 4; ++nt)
                #pragma unroll
                for (int mt = 0; mt < 4; ++mt)
                    acc[mt][nt] = __builtin_amdgcn_mfma_f32_16x16x32_f16(alf[mt], bhf[nt], acc[mt][nt], 0, 0, 0);
        }

        // fold this group's 64 codes into per-row exact top-2
        #pragma unroll
        for (int nt = 0; nt < 4; ++nt) {
            const int code = (wv * 16 + grp * 4 + nt) * 16 + (lane & 15);
            const float c2v = c2[code];
            #pragma unroll
            for (int mt = 0; mt < 4; ++mt) {
                #pragma unroll
                for (int reg = 0; reg < 4; ++reg) {
                    const float d = fmaf(-2.f, acc[mt][nt][reg], c2v);
                    const int qi = mt * 4 + reg;
                    const bool better = (d < q1d[qi]) || (d == q1d[qi] && code < q1i[qi]);
                    const float second = better ? q1d[qi] : d;
                    q2d[qi] = fminf(q2d[qi], second);
                    q1i[qi] = better ? code : q1i[qi];
                    q1d[qi] = better ? d : q1d[qi];
                }
            }
        }
    }

    // cross-lane top-2 reduce over the 16 code-columns (lane&15)
    #pragma unroll
    for (int off = 1; off < 16; off <<= 1) {
        #pragma unroll
        for (int qi = 0; qi < 16; ++qi) {
            const float od1 = __shfl_xor(q1d[qi], off);
            const int   oi1 = __shfl_xor(q1i[qi], off);
            const float od2 = __shfl_xor(q2d[qi], off);
            const bool obetter = (od1 < q1d[qi]) || (od1 == q1d[qi] && oi1 < q1i[qi]);
            const float loser = obetter ? q1d[qi] : od1;
            q2d[qi] = fminf(fminf(q2d[qi], od2), loser);
            q1d[qi] = obetter ? od1 : q1d[qi];
            q1i[qi] = obetter ? oi1 : q1i[qi];
        }
    }
    if ((lane & 15) == 0) {
        #pragma unroll
        for (int qi = 0; qi < 16; ++qi) {
            const int mt = qi >> 2, reg = qi & 3;
            const int row = mt * 16 + (lane >> 4) * 4 + reg;
            q1ds[wv][row] = q1d[qi];
            q1is[wv][row] = q1i[qi];
            q2ds[wv][row] = q2d[qi];
        }
    }
    __syncthreads();
    if (tid < 64) {
        float d1 = q1ds[0][tid]; int i1 = q1is[0][tid]; float d2 = q2ds[0][tid];
        #pragma unroll
        for (int v = 1; v < 4; ++v) {
            const float od1 = q1ds[v][tid]; const int oi1 = q1is[v][tid]; const float od2 = q2ds[v][tid];
            const bool obetter = (od1 < d1) || (od1 == d1 && oi1 < i1);
            const float loser = obetter ? d1 : od1;
            d2 = fminf(fminf(d2, od2), loser);
            d1 = obetter ? od1 : d1;
            i1 = obetter ? oi1 : i1;
        }
        const int grow = bh * 64 + tid;
        idx_int[grow] = i1;
        out[IDX_OFF + grow] = (float)i1;
        if (d2 - d1 < 0.05f) {               // tight gap -> exact fp32 rescore
            const int pos = atomicAdd(cnt, 1);
            rows[pos] = grow;
        }
    }
}

// ---------------------------------------------------------------------------
// Fixup: exact fp32 full-scan argmin for flagged rows, coalesced via cbT.
__global__ __launch_bounds__(256) void fixup(const float* __restrict__ x,
                                             const float* __restrict__ cbT,
                                             const float* __restrict__ c2,
                                             const int* __restrict__ cnt,
                                             const int* __restrict__ rows,
                                             float* __restrict__ out,
                                             int* __restrict__ idx_int) {
    __shared__ float xs[256];
    __shared__ float ds[256];
    __shared__ int kk[256];
    const int t = threadIdx.x;
    const int n = cnt[0];
    for (int i = blockIdx.x; i < n; i += gridDim.x) {
        const int row = rows[i];
        const int b = row >> 12, h = (row >> 6) & 63, w = row & 63;
        __syncthreads();
        xs[t] = x[(((size_t)b * Cd + t) * Hn + h) * Wn + w];
        __syncthreads();
        float dot[4] = {0.f, 0.f, 0.f, 0.f};
        #pragma unroll 8
        for (int c = 0; c < Cd; ++c) {
            const float4 v = ((const float4*)(cbT + (size_t)c * Kc))[t];
            const float xc = xs[c];
            dot[0] = fmaf(v.x, xc, dot[0]);
            dot[1] = fmaf(v.y, xc, dot[1]);
            dot[2] = fmaf(v.z, xc, dot[2]);
            dot[3] = fmaf(v.w, xc, dot[3]);
        }
        float bd = 3.4e38f; int bk = 0;
        #pragma unroll
        for (int j = 0; j < 4; ++j) {
            const int k = t * 4 + j;
            const float d = c2[k] - 2.f * dot[j];
            if (d < bd) { bd = d; bk = k; }
        }
        ds[t] = bd; kk[t] = bk;
        __syncthreads();
        for (int s = 128; s > 0; s >>= 1) {
            if (t < s) {
                const float od = ds[t + s]; const int ok = kk[t + s];
                if (od < ds[t] || (od == ds[t] && ok < kk[t])) { ds[t] = od; kk[t] = ok; }
            }
            __syncthreads();
        }
        if (t == 0) { idx_int[row] = kk[0]; out[IDX_OFF + row] = (float)kk[0]; }
    }
}

// ---------------------------------------------------------------------------
// Epilogue v2: float4 codebook row gather (64 KB/block of L2 traffic instead
// of per-lane scalar lines), coalesced x reads and out writes, losses.
// Thread (w = tid&63, cq = tid>>6) covers c in [cq*64, cq*64+64).
__global__ __launch_bounds__(256) void epilogue(const float* __restrict__ x,
                                                const float* __restrict__ cb,
                                                const int* __restrict__ idx_int,
                                                float* __restrict__ out) {
    __shared__ int idx_s[64];
    __shared__ float red[4];
    const int tid = threadIdx.x;
    const int bh = blockIdx.x;
    const int b = bh >> 6, h = bh & 63;
    if (tid < 64) idx_s[tid] = idx_int[bh * 64 + tid];
    __syncthreads();
    const int w = tid & 63, cq = tid >> 6;
    const int myidx = idx_s[w];
    const float4* cbrow = (const float4*)(cb + (size_t)myidx * Cd + cq * 64);
    const size_t obase = (((size_t)b * Cd + cq * 64) * Hn + h) * Wn + w;
    float lsum = 0.f;
    #pragma unroll 4
    for (int i = 0; i < 16; ++i) {
        const float4 qv = cbrow[i];
        const size_t o = obase + (size_t)(i * 4) * (Hn * Wn);
        const float xv0 = x[o];
        const float xv1 = x[o + 1 * Hn * Wn];
        const float xv2 = x[o + 2 * Hn * Wn];
        const float xv3 = x[o + 3 * Hn * Wn];
        const float d0 = qv.x - xv0, d1 = qv.y - xv1, d2 = qv.z - xv2, d3 = qv.w - xv3;
        lsum += d0 * d0 + d1 * d1 + d2 * d2 + d3 * d3;
        out[o] = qv.x;
        out[o + 1 * Hn * Wn] = qv.y;
        out[o + 2 * Hn * Wn] = qv.z;
        out[o + 3 * Hn * Wn] = qv.w;
    }
    #pragma unroll
    for (int off = 32; off >= 1; off >>= 1) lsum += __shfl_xor(lsum, off);
    if ((tid & 63) == 0) red[tid >> 6] = lsum;
    __syncthreads();
    if (tid == 0) {
        const float s = (red[0] + red[1] + red[2] + red[3]) * (1.0f / 16777216.0f);
        atomicAdd(out + LOSS_OFF, s);
        atomicAdd(out + LOSS_OFF + 1, s);
    }
}

// ---------------------------------------------------------------------------
extern "C" void kernel_launch(void* const* d_in, const int* in_sizes, int n_in,
                              void* d_out, int out_size, void* d_ws, size_t ws_size,
                              hipStream_t stream) {
    const float* x  = (const float*)d_in[0];   // (16,256,64,64)
    const float* cb = (const float*)d_in[1];   // (1024,256)
    float* out = (float*)d_out;
    char* ws = (char*)d_ws;
    _Float16* cbFh = (_Float16*)(ws + WS_CBFH);
    _Float16* cbFl = (_Float16*)(ws + WS_CBFL);
    float* c2      = (float*)(ws + WS_C2);
    int* cnt       = (int*)(ws + WS_CNT);
    int* rows      = (int*)(ws + WS_ROWS);
    int* idx_int   = (int*)(ws + WS_IDX);
    float* cbT     = (float*)(ws + WS_CBT);

    transpose_cb<<<dim3(16, 4), 256, 0, stream>>>(cb, cbT);
    cb_frag<<<128, 256, 0, stream>>>(cb, cbFh, cbFl, cnt);
    c2_kernel<<<256, 256, 0, stream>>>(cb, c2, out);
    vq_main<<<Bn * Hn, 256, 0, stream>>>(x, cbFh, cbFl, c2, out, idx_int, cnt, rows);
    fixup<<<256, 256, 0, stream>>>(x, cbT, c2, cnt, rows, out, idx_int);
    epilogue<<<Bn * Hn, 256, 0, stream>>>(x, cb, idx_int, out);
}

// Round 6
// 266.183 us; speedup vs baseline: 3.7112x; 1.0604x over previous
//
#include <hip/hip_runtime.h>

// Problem constants
constexpr int Bn = 16, Cd = 256, Hn = 64, Wn = 64, Kc = 1024;
constexpr int QUANT_ELEMS = Bn * Hn * Wn * Cd;   // 16777216
constexpr int LOSS_OFF = QUANT_ELEMS;            // +0 codebook_loss, +1 commitment_loss
constexpr int IDX_OFF = QUANT_ELEMS + 2;         // 65536 indices (stored as float)

typedef _Float16 half8 __attribute__((ext_vector_type(8)));
typedef float f32x4 __attribute__((ext_vector_type(4)));

// ws layout (bytes):
constexpr size_t WS_CBFH = 0;                            // 512 KB fp16 hi codebook (B-frag)
constexpr size_t WS_CBFL = 512 * 1024;                   // 512 KB fp16 lo residual
constexpr size_t WS_C2   = 1024 * 1024;                  // 4 KB
constexpr size_t WS_CNT  = 1024 * 1024 + 4096;           // 4 B flagged count
constexpr size_t WS_ROWS = 1024 * 1024 + 8192;           // 256 KB flagged rows
constexpr size_t WS_IDX  = 1024 * 1024 + 8192 + 262144;  // 256 KB final int idx
constexpr size_t WS_CBT  = 1024 * 1024 + 8192 + 524288;  // 1 MB cbT (C,K) fp32

// ---------------------------------------------------------------------------
// Merged prep: one kernel produces cbT (C,K), cbFh/cbFl (B-fragment fp16
// hi/lo), c2, and zeroes cnt + loss outputs. Block = 64 codes.
__global__ __launch_bounds__(256) void prep(const float* __restrict__ cb,
                                            float* __restrict__ cbT,
                                            _Float16* __restrict__ cbFh,
                                            _Float16* __restrict__ cbFl,
                                            float* __restrict__ c2,
                                            int* __restrict__ cnt,
                                            float* __restrict__ out) {
    __shared__ float cbs[64][257];   // 64 codes x 256 c, +1 pad
    const int tid = threadIdx.x;
    const int k0 = blockIdx.x * 64;  // 16 blocks
    {   // load tile, coalesced along c
        const int c4 = (tid & 63) * 4;
        const int r0 = tid >> 6;
        #pragma unroll
        for (int it = 0; it < 16; ++it) {
            const int r = r0 + it * 4;
            const float4 v = *(const float4*)&cb[(size_t)(k0 + r) * Cd + c4];
            cbs[r][c4] = v.x; cbs[r][c4 + 1] = v.y; cbs[r][c4 + 2] = v.z; cbs[r][c4 + 3] = v.w;
        }
    }
    __syncthreads();
    {   // cbT: coalesced along k
        const int kk = tid & 63, j0 = tid >> 6;
        for (int j = j0; j < 256; j += 4)
            cbT[(size_t)j * Kc + k0 + kk] = cbs[kk][j];
    }
    {   // c2: 4 threads per code
        const int i = tid >> 2, part = tid & 3;
        float s = 0.f;
        for (int c = part * 64; c < part * 64 + 64; ++c) { const float v = cbs[i][c]; s += v * v; }
        s += __shfl_xor(s, 1);
        s += __shfl_xor(s, 2);
        if (part == 0) c2[k0 + i] = s;
    }
    // fragments: B frag (16x16x32 f16): lane l holds B[k=(l>>4)*8+j][n=l&15]
    for (int t = tid; t < 2048; t += 256) {
        const int ntl = t >> 9;          // 0..3
        const int kblk = (t >> 6) & 7;
        const int l = t & 63;
        const int code_l = ntl * 16 + (l & 15);
        const int cbase = kblk * 32 + (l >> 4) * 8;
        half8 hv, lv;
        #pragma unroll
        for (int j = 0; j < 8; ++j) {
            const float v = cbs[code_l][cbase + j];
            const _Float16 hh = (_Float16)v;
            hv[j] = hh;
            lv[j] = (_Float16)(v - (float)hh);
        }
        const size_t e = (size_t)(((k0 >> 4) + ntl) * 8 + kblk) * 64 + l;
        *(half8*)(cbFh + e * 8) = hv;
        *(half8*)(cbFl + e * 8) = lv;
    }
    if (blockIdx.x == 0 && tid == 0) {
        cnt[0] = 0; out[LOSS_OFF] = 0.f; out[LOSS_OFF + 1] = 0.f;
    }
}

// ---------------------------------------------------------------------------
// Main MFMA kernel v4. Block = one (b,h) = 64 rows x 256 c.
// - x staged once, fp16 hi/lo split, A-fragment-linear LDS (64 KB).
// - 2 MFMA terms (hh + hl = xh*c); dropped xl*c has pairwise-diff sigma
//   ~0.013 -> flag threshold 0.12 (~9 sigma), flagged rows get exact fixup.
// - Barrier-free K-loop; exact top-2 (no tie-break: ties => gap 0 => flagged).
// - FUSED epilogue: quant gather + coalesced write + loss from LDS-x.
__global__ __launch_bounds__(256, 2) void vq_main(const float* __restrict__ x,
                                                  const _Float16* __restrict__ cbFh,
                                                  const _Float16* __restrict__ cbFl,
                                                  const float* __restrict__ c2,
                                                  const float* __restrict__ cb,
                                                  float* __restrict__ out,
                                                  int* __restrict__ idx_int,
                                                  int* __restrict__ cnt,
                                                  int* __restrict__ rows) {
    __shared__ half8 Axh[2048];   // 32 KB: [kblk 8][mt 4][lane 64]
    __shared__ half8 Axl[2048];   // 32 KB
    __shared__ float q1ds[4][64];
    __shared__ int   q1is[4][64];
    __shared__ float q2ds[4][64];
    __shared__ int   idx_s[64];
    __shared__ float red[4];

    const int tid = threadIdx.x;
    const int lane = tid & 63;
    const int wv = tid >> 6;
    const int bh = blockIdx.x;
    const int b = bh >> 6, h = bh & 63;

    // ---- Stage x-tile once: gather + fp16 split + lane-contiguous b128 writes
    {
        const int m = tid & 15;           // row within m-tile
        const int q = (tid >> 4) & 3;     // k-quad
        const int mt = tid >> 6;          // m-tile
        const int w = mt * 16 + m;
        const float* xb = x + ((size_t)b * Cd * Hn + h) * Wn + w;   // + c*4096
        #pragma unroll
        for (int kblk = 0; kblk < 8; ++kblk) {
            half8 hv, lv;
            #pragma unroll
            for (int j = 0; j < 8; ++j) {
                const int c = kblk * 32 + q * 8 + j;
                const float v = xb[(size_t)c * (Hn * Wn)];
                const _Float16 hh = (_Float16)v;
                hv[j] = hh;
                lv[j] = (_Float16)(v - (float)hh);
            }
            const int e = (kblk * 4 + mt) * 64 + (q * 16 + m);   // == ...*64 + lane
            Axh[e] = hv;
            Axl[e] = lv;
        }
    }
    __syncthreads();

    float q1d[16], q2d[16];
    int   q1i[16];
    #pragma unroll
    for (int i = 0; i < 16; ++i) { q1d[i] = 3.4e38f; q2d[i] = 3.4e38f; q1i[i] = 0; }

    #pragma unroll 1
    for (int grp = 0; grp < 4; ++grp) {
        f32x4 acc[4][4];   // [mt][nt]
        #pragma unroll
        for (int mt = 0; mt < 4; ++mt)
            #pragma unroll
            for (int nt = 0; nt < 4; ++nt) acc[mt][nt] = (f32x4){0.f, 0.f, 0.f, 0.f};

        #pragma unroll 2
        for (int kblk = 0; kblk < 8; ++kblk) {
            half8 bhf[4], blf[4];
            #pragma unroll
            for (int nt = 0; nt < 4; ++nt) {
                const int ntile = wv * 16 + grp * 4 + nt;
                const size_t be = ((size_t)(ntile * 8 + kblk) * 64 + lane) * 8;
                bhf[nt] = *(const half8*)(cbFh + be);
                blf[nt] = *(const half8*)(cbFl + be);
            }
            half8 ahf[4];
            #pragma unroll
            for (int mt = 0; mt < 4; ++mt) {
                const int e = (kblk * 4 + mt) * 64 + lane;
                ahf[mt] = Axh[e];
            }
            // 2 terms: xh*ch + xh*cl = xh*c
            #pragma unroll
            for (int nt = 0; nt < 4; ++nt)
                #pragma unroll
                for (int mt = 0; mt < 4; ++mt)
                    acc[mt][nt] = __builtin_amdgcn_mfma_f32_16x16x32_f16(ahf[mt], bhf[nt], acc[mt][nt], 0, 0, 0);
            #pragma unroll
            for (int nt = 0; nt < 4; ++nt)
                #pragma unroll
                for (int mt = 0; mt < 4; ++mt)
                    acc[mt][nt] = __builtin_amdgcn_mfma_f32_16x16x32_f16(ahf[mt], blf[nt], acc[mt][nt], 0, 0, 0);
        }

        // fold this group's 64 codes into per-row top-2 (no tie-break)
        #pragma unroll
        for (int nt = 0; nt < 4; ++nt) {
            const int code = (wv * 16 + grp * 4 + nt) * 16 + (lane & 15);
            const float c2v = c2[code];
            #pragma unroll
            for (int mt = 0; mt < 4; ++mt) {
                #pragma unroll
                for (int reg = 0; reg < 4; ++reg) {
                    const float d = fmaf(-2.f, acc[mt][nt][reg], c2v);
                    const int qi = mt * 4 + reg;
                    const bool better = d < q1d[qi];
                    const float second = better ? q1d[qi] : d;
                    q2d[qi] = fminf(q2d[qi], second);
                    q1i[qi] = better ? code : q1i[qi];
                    q1d[qi] = fminf(q1d[qi], d);
                }
            }
        }
    }

    // cross-lane top-2 reduce over the 16 code-columns (lane&15)
    #pragma unroll
    for (int off = 1; off < 16; off <<= 1) {
        #pragma unroll
        for (int qi = 0; qi < 16; ++qi) {
            const float od1 = __shfl_xor(q1d[qi], off);
            const int   oi1 = __shfl_xor(q1i[qi], off);
            const float od2 = __shfl_xor(q2d[qi], off);
            const bool obetter = od1 < q1d[qi];
            const float loser = obetter ? q1d[qi] : od1;
            q2d[qi] = fminf(fminf(q2d[qi], od2), loser);
            q1d[qi] = obetter ? od1 : q1d[qi];
            q1i[qi] = obetter ? oi1 : q1i[qi];
        }
    }
    if ((lane & 15) == 0) {
        #pragma unroll
        for (int qi = 0; qi < 16; ++qi) {
            const int mt = qi >> 2, reg = qi & 3;
            const int row = mt * 16 + (lane >> 4) * 4 + reg;
            q1ds[wv][row] = q1d[qi];
            q1is[wv][row] = q1i[qi];
            q2ds[wv][row] = q2d[qi];
        }
    }
    __syncthreads();
    if (tid < 64) {
        float d1 = q1ds[0][tid]; int i1 = q1is[0][tid]; float d2 = q2ds[0][tid];
        #pragma unroll
        for (int v = 1; v < 4; ++v) {
            const float od1 = q1ds[v][tid]; const int oi1 = q1is[v][tid]; const float od2 = q2ds[v][tid];
            const bool obetter = od1 < d1;
            const float loser = obetter ? d1 : od1;
            d2 = fminf(fminf(d2, od2), loser);
            d1 = obetter ? od1 : d1;
            i1 = obetter ? oi1 : i1;
        }
        const int grow = bh * 64 + tid;
        idx_s[tid] = i1;
        idx_int[grow] = i1;
        out[IDX_OFF + grow] = (float)i1;
        if (d2 - d1 < 0.12f) {               // tight gap -> exact fp32 rescore
            const int pos = atomicAdd(cnt, 1);
            rows[pos] = grow;
        }
    }
    __syncthreads();

    // ---- Fused epilogue: quant gather (L2-resident cb), coalesced writes,
    //      loss from LDS-reconstructed x (xh+xl, error ~2^-24).
    {
        const int w = tid & 63;           // row
        const int cq = wv;                // c-quarter: c in [cq*64, cq*64+64)
        const int m = w & 15, mt = w >> 4;
        const int myidx = idx_s[w];
        const float4* cbrow = (const float4*)(cb + (size_t)myidx * Cd + cq * 64);
        float lsum = 0.f;
        #pragma unroll
        for (int half = 0; half < 2; ++half) {
            const int kblk = cq * 2 + half;
            #pragma unroll
            for (int q = 0; q < 4; ++q) {
                const int e = (kblk * 4 + mt) * 64 + q * 16 + m;
                const half8 hv = Axh[e];
                const half8 lv = Axl[e];
                const float4 qa = cbrow[half * 8 + q * 2];
                const float4 qb = cbrow[half * 8 + q * 2 + 1];
                const float qv[8] = {qa.x, qa.y, qa.z, qa.w, qb.x, qb.y, qb.z, qb.w};
                const int cbase = cq * 64 + half * 32 + q * 8;
                #pragma unroll
                for (int j = 0; j < 8; ++j) {
                    const float xv = (float)hv[j] + (float)lv[j];
                    const float dd = qv[j] - xv;
                    lsum += dd * dd;
                    out[(((size_t)b * Cd + cbase + j) * Hn + h) * Wn + w] = qv[j];
                }
            }
        }
        #pragma unroll
        for (int off = 32; off >= 1; off >>= 1) lsum += __shfl_xor(lsum, off);
        if (lane == 0) red[wv] = lsum;
    }
    __syncthreads();
    if (tid == 0) {
        const float s = (red[0] + red[1] + red[2] + red[3]) * (1.0f / 16777216.0f);
        atomicAdd(out + LOSS_OFF, s);
        atomicAdd(out + LOSS_OFF + 1, s);
    }
}

// ---------------------------------------------------------------------------
// Fixup v4: exact fp32 full-scan argmin for flagged rows (coalesced via cbT);
// if the index changed, also repair the quant row and the losses.
__global__ __launch_bounds__(256) void fixup(const float* __restrict__ x,
                                             const float* __restrict__ cbT,
                                             const float* __restrict__ cb,
                                             const float* __restrict__ c2,
                                             const int* __restrict__ cnt,
                                             const int* __restrict__ rows,
                                             float* __restrict__ out,
                                             int* __restrict__ idx_int) {
    __shared__ float xs[256];
    __shared__ float ds[256];
    __shared__ int kk[256];
    __shared__ int s_old;
    const int t = threadIdx.x;
    const int n = cnt[0];
    for (int i = blockIdx.x; i < n; i += gridDim.x) {
        const int row = rows[i];
        const int b = row >> 12, h = (row >> 6) & 63, w = row & 63;
        __syncthreads();
        xs[t] = x[(((size_t)b * Cd + t) * Hn + h) * Wn + w];
        if (t == 0) s_old = idx_int[row];
        __syncthreads();
        float dot[4] = {0.f, 0.f, 0.f, 0.f};
        #pragma unroll 8
        for (int c = 0; c < Cd; ++c) {
            const float4 v = ((const float4*)(cbT + (size_t)c * Kc))[t];
            const float xc = xs[c];
            dot[0] = fmaf(v.x, xc, dot[0]);
            dot[1] = fmaf(v.y, xc, dot[1]);
            dot[2] = fmaf(v.z, xc, dot[2]);
            dot[3] = fmaf(v.w, xc, dot[3]);
        }
        float bd = 3.4e38f; int bk = 0;
        #pragma unroll
        for (int j = 0; j < 4; ++j) {
            const int k = t * 4 + j;
            const float d = c2[k] - 2.f * dot[j];
            if (d < bd) { bd = d; bk = k; }
        }
        ds[t] = bd; kk[t] = bk;
        __syncthreads();
        for (int s = 128; s > 0; s >>= 1) {
            if (t < s) {
                const float od = ds[t + s]; const int ok = kk[t + s];
                if (od < ds[t] || (od == ds[t] && ok < kk[t])) { ds[t] = od; kk[t] = ok; }
            }
            __syncthreads();
        }
        const int kn = kk[0], ko = s_old;
        if (t == 0 && kn != ko) { idx_int[row] = kn; out[IDX_OFF + row] = (float)kn; }
        if (kn != ko) {   // block-uniform: repair quant row + losses
            const float qn = cb[(size_t)kn * Cd + t];
            const float qo = cb[(size_t)ko * Cd + t];
            const float xv = xs[t];
            const float dn = qn - xv, dold = qo - xv;
            float delta = dn * dn - dold * dold;
            out[(((size_t)b * Cd + t) * Hn + h) * Wn + w] = qn;
            #pragma unroll
            for (int off = 32; off >= 1; off >>= 1) delta += __shfl_xor(delta, off);
            ds[t] = 0.f;  // reuse as scratch after barrier
            __syncthreads();
            if ((t & 63) == 0) ds[t >> 6] = delta;
            __syncthreads();
            if (t == 0) {
                const float s = (ds[0] + ds[1] + ds[2] + ds[3]) * (1.0f / 16777216.0f);
                atomicAdd(out + LOSS_OFF, s);
                atomicAdd(out + LOSS_OFF + 1, s);
            }
        }
    }
}

// ---------------------------------------------------------------------------
extern "C" void kernel_launch(void* const* d_in, const int* in_sizes, int n_in,
                              void* d_out, int out_size, void* d_ws, size_t ws_size,
                              hipStream_t stream) {
    const float* x  = (const float*)d_in[0];   // (16,256,64,64)
    const float* cb = (const float*)d_in[1];   // (1024,256)
    float* out = (float*)d_out;
    char* ws = (char*)d_ws;
    _Float16* cbFh = (_Float16*)(ws + WS_CBFH);
    _Float16* cbFl = (_Float16*)(ws + WS_CBFL);
    float* c2      = (float*)(ws + WS_C2);
    int* cnt       = (int*)(ws + WS_CNT);
    int* rows      = (int*)(ws + WS_ROWS);
    int* idx_int   = (int*)(ws + WS_IDX);
    float* cbT     = (float*)(ws + WS_CBT);

    prep<<<16, 256, 0, stream>>>(cb, cbT, cbFh, cbFl, c2, cnt, out);
    vq_main<<<Bn * Hn, 256, 0, stream>>>(x, cbFh, cbFl, c2, cb, out, idx_int, cnt, rows);
    fixup<<<256, 256, 0, stream>>>(x, cbT, cb, c2, cnt, rows, out, idx_int);
}